// Round 1
// baseline (59.945 us; speedup 1.0000x reference)
//
#include <hip/hip_runtime.h>

namespace {

constexpr int kS = 7;
constexpr int kB = 2;
constexpr int kC = 20;
constexpr int kN = 8;
constexpr int kBS = 16384;
constexpr int kCells = kBS * kS * kS;          // 802816, divisible by 256
constexpr float kLambdaCoord = 5.0f;
constexpr float kLambdaNoobj = 0.5f;
constexpr float kEps = 1e-6f;

__global__ void zero_kernel(float* out) {
  if (threadIdx.x == 0) out[0] = 0.0f;
}

__global__ __launch_bounds__(256) void yolo_loss_kernel(
    const float* __restrict__ outputs,   // [BS,7,7,30]
    const float* __restrict__ gt_boxes,  // [BS,8,4]
    const int* __restrict__ gt_labels,   // [BS,8]
    float* __restrict__ out) {
  const int c = blockIdx.x * 256 + threadIdx.x;
  float val = 0.0f;
  if (c < kCells) {
    const int bs = c / (kS * kS);
    const float* cell = outputs + (size_t)c * (kB * 5 + kC);

    // ---- load the 30 floats of this cell (120 B, 8B-aligned -> float2) ----
    float x[30];
    const float2* p2 = reinterpret_cast<const float2*>(cell);
#pragma unroll
    for (int i = 0; i < 15; ++i) {
      float2 v = p2[i];
      x[2 * i + 0] = v.x;
      x[2 * i + 1] = v.y;
    }

    // ---- load 8 gt boxes (128 B per batch, 16B-aligned -> float4) ----
    float g[kN][4];
    const float4* gb4 = reinterpret_cast<const float4*>(gt_boxes + (size_t)bs * kN * 4);
#pragma unroll
    for (int n = 0; n < kN; ++n) {
      float4 v = gb4[n];
      g[n][0] = v.x; g[n][1] = v.y; g[n][2] = v.z; g[n][3] = v.w;
    }

    // ---- pairwise IOU iou[b][n] ----
    float iou[kB][kN];
#pragma unroll
    for (int b = 0; b < kB; ++b) {
      const float px = x[b * 5 + 0], py = x[b * 5 + 1];
      const float pw = x[b * 5 + 2], ph = x[b * 5 + 3];
      const float px1 = px - pw * 0.5f, px2 = px + pw * 0.5f;
      const float py1 = py - ph * 0.5f, py2 = py + ph * 0.5f;
      const float parea = pw * ph;
#pragma unroll
      for (int n = 0; n < kN; ++n) {
        const float gx = g[n][0], gy = g[n][1], gw = g[n][2], gh = g[n][3];
        const float gx1 = gx - gw * 0.5f, gx2 = gx + gw * 0.5f;
        const float gy1 = gy - gh * 0.5f, gy2 = gy + gh * 0.5f;
        const float iw = fmaxf(fminf(px2, gx2) - fmaxf(px1, gx1), 0.0f);
        const float ih = fmaxf(fminf(py2, gy2) - fmaxf(py1, gy1), 0.0f);
        const float inter = iw * ih;
        const float uni = parea + gw * gh - inter;
        iou[b][n] = inter / (uni + kEps);
      }
    }

    // ---- j_star = first argmax_n of max_b iou; track iou[:,j_star] as we scan
    //      (keeps all indexing compile-time -> no scratch) ----
    float best_iou = -1.0f;
    float i0j = 0.0f, i1j = 0.0f;
#pragma unroll
    for (int n = 0; n < kN; ++n) {
      const float m = fmaxf(iou[0][n], iou[1][n]);
      if (m > best_iou) {   // strict >: first max wins, matches jnp.argmax
        best_iou = m;
        i0j = iou[0][n];
        i1j = iou[1][n];
      }
    }
    // best_b = argmax over B of iou[:, j_star]; index 0 wins ties
    const int bb = (i1j > i0j) ? 1 : 0;

    // ---- selections ----
    // NOTE reference quirk: gt_sel indexes gt_boxes' N axis with best_b (0/1)
    const float gsx = bb ? g[1][0] : g[0][0];
    const float gsy = bb ? g[1][1] : g[0][1];
    const float gsw = bb ? g[1][2] : g[0][2];
    const float gsh = bb ? g[1][3] : g[0][3];
    const float psx = bb ? x[5] : x[0];
    const float psy = bb ? x[6] : x[1];
    const float psw = bb ? x[7] : x[2];
    const float psh = bb ? x[8] : x[3];
    const float psc = bb ? x[9] : x[4];

    // ---- localization + confidence ----
    const float dx = psx - gsx;
    const float dy = psy - gsy;
    const float dw = sqrtf(psw) - sqrtf(gsw);
    const float dh = sqrtf(psh) - sqrtf(gsh);
    const float loc = kLambdaCoord * (dx * dx + dy * dy + dw * dw + dh * dh);
    const float conf_obj = (psc - best_iou) * (psc - best_iou);

    // ---- log-softmax over the 20 classes ----
    float mx = x[10];
#pragma unroll
    for (int k = 1; k < kC; ++k) mx = fmaxf(mx, x[10 + k]);
    float se = 0.0f;
#pragma unroll
    for (int k = 0; k < kC; ++k) se += __expf(x[10 + k] - mx);
    const float lse = mx + __logf(se);

    // ---- CE: mean over the 8 labels (gather re-reads cell from L1;
    //      avoids runtime-indexing the x[] register array) ----
    const int* labp = gt_labels + (size_t)bs * kN;
    float ce = 0.0f;
#pragma unroll
    for (int n = 0; n < kN; ++n) {
      const int lab = labp[n];
      ce += cell[10 + lab] - lse;
    }
    ce = -ce * (1.0f / kN);

    // ---- noobj ----
    const float noobj = kLambdaNoobj * (x[4] * x[4] + x[9] * x[9]);

    val = (best_iou > 0.0f) ? (loc + conf_obj + ce) : noobj;
  }

  // ---- block reduction: wave64 shuffle, then LDS across the 4 waves ----
#pragma unroll
  for (int off = 32; off > 0; off >>= 1) val += __shfl_down(val, off, 64);
  __shared__ float ws[4];
  const int lane = threadIdx.x & 63;
  const int wid = threadIdx.x >> 6;
  if (lane == 0) ws[wid] = val;
  __syncthreads();
  if (threadIdx.x == 0) {
    const float s = ws[0] + ws[1] + ws[2] + ws[3];
    atomicAdd(out, s * (1.0f / kBS));  // exact 2^-14 scale
  }
}

}  // namespace

extern "C" void kernel_launch(void* const* d_in, const int* in_sizes, int n_in,
                              void* d_out, int out_size, void* d_ws, size_t ws_size,
                              hipStream_t stream) {
  const float* outputs = (const float*)d_in[0];
  const float* gt_boxes = (const float*)d_in[1];
  const int* gt_labels = (const int*)d_in[2];
  float* out = (float*)d_out;

  zero_kernel<<<1, 64, 0, stream>>>(out);
  yolo_loss_kernel<<<kCells / 256, 256, 0, stream>>>(outputs, gt_boxes, gt_labels, out);
}

// Round 2
// 59.332 us; speedup vs baseline: 1.0103x; 1.0103x over previous
//
#include <hip/hip_runtime.h>

namespace {

constexpr int kS = 7;
constexpr int kB = 2;
constexpr int kC = 20;
constexpr int kN = 8;
constexpr int kBS = 16384;
constexpr int kCells = kBS * kS * kS;          // 802816 = 3136 * 256 exactly
constexpr int kF = kB * 5 + kC;                // 30 floats per cell
constexpr float kLambdaCoord = 5.0f;
constexpr float kLambdaNoobj = 0.5f;
constexpr float kEps = 1e-6f;

__global__ void zero_kernel(float* out) {
  if (threadIdx.x == 0) out[0] = 0.0f;
}

__global__ __launch_bounds__(256) void yolo_loss_kernel(
    const float* __restrict__ outputs,   // [BS,7,7,30]
    const float* __restrict__ gt_boxes,  // [BS,8,4]
    const int* __restrict__ gt_labels,   // [BS,8]
    float* __restrict__ out) {
  __shared__ float lds[256 * kF];        // 30 KB: one block = 256 cells

  const int tid = threadIdx.x;
  const int c0 = blockIdx.x * 256;
  const int c = c0 + tid;
  const int bs = c / (kS * kS);

  // ---- issue per-thread gt loads FIRST so their latency hides under staging.
  //      49 consecutive threads share a batch -> near-broadcast, L1-friendly.
  float g[kN][4];
  const float4* gb4 = reinterpret_cast<const float4*>(gt_boxes + (size_t)bs * kN * 4);
#pragma unroll
  for (int n = 0; n < kN; ++n) {
    float4 v = gb4[n];
    g[n][0] = v.x; g[n][1] = v.y; g[n][2] = v.z; g[n][3] = v.w;
  }
  const int4* lb4 = reinterpret_cast<const int4*>(gt_labels + (size_t)bs * kN);
  const int4 lab0 = lb4[0];
  const int4 lab1 = lb4[1];

  // ---- stage this block's 256 cells into LDS, fully coalesced float4 ----
  //      256 cells * 30 floats = 7680 floats = 1920 float4.
  {
    const float4* src = reinterpret_cast<const float4*>(outputs + (size_t)c0 * kF);
    float4* dst = reinterpret_cast<float4*>(lds);
#pragma unroll
    for (int i = tid; i < 1920; i += 256) dst[i] = src[i];
  }
  __syncthreads();

  // per-thread cell view in LDS; word-stride 30 across lanes -> 2-way bank
  // aliasing only (free on CDNA4)
  const float* x = lds + tid * kF;

  // ---- pairwise IOU iou[b][n] ----
  float iou[kB][kN];
#pragma unroll
  for (int b = 0; b < kB; ++b) {
    const float px = x[b * 5 + 0], py = x[b * 5 + 1];
    const float pw = x[b * 5 + 2], ph = x[b * 5 + 3];
    const float px1 = px - pw * 0.5f, px2 = px + pw * 0.5f;
    const float py1 = py - ph * 0.5f, py2 = py + ph * 0.5f;
    const float parea = pw * ph;
#pragma unroll
    for (int n = 0; n < kN; ++n) {
      const float gx = g[n][0], gy = g[n][1], gw = g[n][2], gh = g[n][3];
      const float gx1 = gx - gw * 0.5f, gx2 = gx + gw * 0.5f;
      const float gy1 = gy - gh * 0.5f, gy2 = gy + gh * 0.5f;
      const float iw = fmaxf(fminf(px2, gx2) - fmaxf(px1, gx1), 0.0f);
      const float ih = fmaxf(fminf(py2, gy2) - fmaxf(py1, gy1), 0.0f);
      const float inter = iw * ih;
      const float uni = parea + gw * gh - inter;
      iou[b][n] = inter / (uni + kEps);
    }
  }

  // ---- j_star scan (first-max wins, matches jnp.argmax) ----
  float best_iou = -1.0f;
  float i0j = 0.0f, i1j = 0.0f;
#pragma unroll
  for (int n = 0; n < kN; ++n) {
    const float m = fmaxf(iou[0][n], iou[1][n]);
    if (m > best_iou) {
      best_iou = m;
      i0j = iou[0][n];
      i1j = iou[1][n];
    }
  }
  const int bb = (i1j > i0j) ? 1 : 0;   // index 0 wins ties

  // ---- selections (reference quirk: best_b indexes gt_boxes' N axis) ----
  const float gsx = bb ? g[1][0] : g[0][0];
  const float gsy = bb ? g[1][1] : g[0][1];
  const float gsw = bb ? g[1][2] : g[0][2];
  const float gsh = bb ? g[1][3] : g[0][3];
  const float psx = bb ? x[5] : x[0];
  const float psy = bb ? x[6] : x[1];
  const float psw = bb ? x[7] : x[2];
  const float psh = bb ? x[8] : x[3];
  const float psc = bb ? x[9] : x[4];

  // ---- localization + confidence ----
  const float dx = psx - gsx;
  const float dy = psy - gsy;
  const float dw = sqrtf(psw) - sqrtf(gsw);
  const float dh = sqrtf(psh) - sqrtf(gsh);
  const float loc = kLambdaCoord * (dx * dx + dy * dy + dw * dw + dh * dh);
  const float conf_obj = (psc - best_iou) * (psc - best_iou);

  // ---- log-softmax over the 20 classes ----
  float mx = x[10];
#pragma unroll
  for (int k = 1; k < kC; ++k) mx = fmaxf(mx, x[10 + k]);
  float se = 0.0f;
#pragma unroll
  for (int k = 0; k < kC; ++k) se += __expf(x[10 + k] - mx);
  const float lse = mx + __logf(se);

  // ---- CE: mean over the 8 labels; dynamic LDS index (no scratch) ----
  float ce = 0.0f;
  ce += x[10 + lab0.x] + x[10 + lab0.y] + x[10 + lab0.z] + x[10 + lab0.w];
  ce += x[10 + lab1.x] + x[10 + lab1.y] + x[10 + lab1.z] + x[10 + lab1.w];
  ce = -(ce - 8.0f * lse) * (1.0f / kN);

  // ---- noobj ----
  const float noobj = kLambdaNoobj * (x[4] * x[4] + x[9] * x[9]);

  float val = (best_iou > 0.0f) ? (loc + conf_obj + ce) : noobj;

  // ---- block reduction: wave64 shuffle, then LDS across the 4 waves ----
#pragma unroll
  for (int off = 32; off > 0; off >>= 1) val += __shfl_down(val, off, 64);
  __shared__ float ws[4];
  const int lane = tid & 63;
  const int wid = tid >> 6;
  if (lane == 0) ws[wid] = val;
  __syncthreads();
  if (tid == 0) {
    const float s = ws[0] + ws[1] + ws[2] + ws[3];
    atomicAdd(out, s * (1.0f / kBS));  // exact 2^-14 scale
  }
}

}  // namespace

extern "C" void kernel_launch(void* const* d_in, const int* in_sizes, int n_in,
                              void* d_out, int out_size, void* d_ws, size_t ws_size,
                              hipStream_t stream) {
  const float* outputs = (const float*)d_in[0];
  const float* gt_boxes = (const float*)d_in[1];
  const int* gt_labels = (const int*)d_in[2];
  float* out = (float*)d_out;

  zero_kernel<<<1, 64, 0, stream>>>(out);
  yolo_loss_kernel<<<kCells / 256, 256, 0, stream>>>(outputs, gt_boxes, gt_labels, out);
}

// Round 3
// 42.396 us; speedup vs baseline: 1.4139x; 1.3995x over previous
//
#include <hip/hip_runtime.h>

namespace {

constexpr int kS = 7;
constexpr int kB = 2;
constexpr int kC = 20;
constexpr int kN = 8;
constexpr int kBS = 16384;
constexpr int kCells = kBS * kS * kS;          // 802816 = 3136 * 256 exactly
constexpr int kBlocks = kCells / 256;          // 3136
constexpr float kLambdaCoord = 5.0f;
constexpr float kLambdaNoobj = 0.5f;
constexpr float kEps = 1e-6f;

__global__ __launch_bounds__(256) void yolo_loss_kernel(
    const float* __restrict__ outputs,   // [BS,7,7,30]
    const float* __restrict__ gt_boxes,  // [BS,8,4]
    const int* __restrict__ gt_labels,   // [BS,8]
    float* __restrict__ partials) {      // [kBlocks]
  const int c = blockIdx.x * 256 + threadIdx.x;
  const int bs = c / (kS * kS);
  const float* cell = outputs + (size_t)c * (kB * 5 + kC);

  // ---- load the 30 floats of this cell (120 B, 8B-aligned -> float2) ----
  float x[30];
  const float2* p2 = reinterpret_cast<const float2*>(cell);
#pragma unroll
  for (int i = 0; i < 15; ++i) {
    float2 v = p2[i];
    x[2 * i + 0] = v.x;
    x[2 * i + 1] = v.y;
  }

  // ---- load 8 gt boxes (128 B per batch, 16B-aligned -> float4) ----
  float g[kN][4];
  const float4* gb4 = reinterpret_cast<const float4*>(gt_boxes + (size_t)bs * kN * 4);
#pragma unroll
  for (int n = 0; n < kN; ++n) {
    float4 v = gb4[n];
    g[n][0] = v.x; g[n][1] = v.y; g[n][2] = v.z; g[n][3] = v.w;
  }

  // ---- pairwise IOU iou[b][n] ----
  float iou[kB][kN];
#pragma unroll
  for (int b = 0; b < kB; ++b) {
    const float px = x[b * 5 + 0], py = x[b * 5 + 1];
    const float pw = x[b * 5 + 2], ph = x[b * 5 + 3];
    const float px1 = px - pw * 0.5f, px2 = px + pw * 0.5f;
    const float py1 = py - ph * 0.5f, py2 = py + ph * 0.5f;
    const float parea = pw * ph;
#pragma unroll
    for (int n = 0; n < kN; ++n) {
      const float gx = g[n][0], gy = g[n][1], gw = g[n][2], gh = g[n][3];
      const float gx1 = gx - gw * 0.5f, gx2 = gx + gw * 0.5f;
      const float gy1 = gy - gh * 0.5f, gy2 = gy + gh * 0.5f;
      const float iw = fmaxf(fminf(px2, gx2) - fmaxf(px1, gx1), 0.0f);
      const float ih = fmaxf(fminf(py2, gy2) - fmaxf(py1, gy1), 0.0f);
      const float inter = iw * ih;
      const float uni = parea + gw * gh - inter;
      iou[b][n] = inter / (uni + kEps);
    }
  }

  // ---- j_star scan (first-max wins, matches jnp.argmax) ----
  float best_iou = -1.0f;
  float i0j = 0.0f, i1j = 0.0f;
#pragma unroll
  for (int n = 0; n < kN; ++n) {
    const float m = fmaxf(iou[0][n], iou[1][n]);
    if (m > best_iou) {
      best_iou = m;
      i0j = iou[0][n];
      i1j = iou[1][n];
    }
  }
  const int bb = (i1j > i0j) ? 1 : 0;   // index 0 wins ties

  // ---- selections (reference quirk: best_b indexes gt_boxes' N axis) ----
  const float gsx = bb ? g[1][0] : g[0][0];
  const float gsy = bb ? g[1][1] : g[0][1];
  const float gsw = bb ? g[1][2] : g[0][2];
  const float gsh = bb ? g[1][3] : g[0][3];
  const float psx = bb ? x[5] : x[0];
  const float psy = bb ? x[6] : x[1];
  const float psw = bb ? x[7] : x[2];
  const float psh = bb ? x[8] : x[3];
  const float psc = bb ? x[9] : x[4];

  // ---- localization + confidence ----
  const float dx = psx - gsx;
  const float dy = psy - gsy;
  const float dw = sqrtf(psw) - sqrtf(gsw);
  const float dh = sqrtf(psh) - sqrtf(gsh);
  const float loc = kLambdaCoord * (dx * dx + dy * dy + dw * dw + dh * dh);
  const float conf_obj = (psc - best_iou) * (psc - best_iou);

  // ---- log-softmax over the 20 classes ----
  float mx = x[10];
#pragma unroll
  for (int k = 1; k < kC; ++k) mx = fmaxf(mx, x[10 + k]);
  float se = 0.0f;
#pragma unroll
  for (int k = 0; k < kC; ++k) se += __expf(x[10 + k] - mx);
  const float lse = mx + __logf(se);

  // ---- CE: mean over the 8 labels (gather re-reads cell from L1) ----
  const int* labp = gt_labels + (size_t)bs * kN;
  float ce = 0.0f;
#pragma unroll
  for (int n = 0; n < kN; ++n) {
    const int lab = labp[n];
    ce += cell[10 + lab] - lse;
  }
  ce = -ce * (1.0f / kN);

  // ---- noobj ----
  const float noobj = kLambdaNoobj * (x[4] * x[4] + x[9] * x[9]);

  float val = (best_iou > 0.0f) ? (loc + conf_obj + ce) : noobj;

  // ---- block reduction: wave64 shuffle, then LDS across the 4 waves ----
#pragma unroll
  for (int off = 32; off > 0; off >>= 1) val += __shfl_down(val, off, 64);
  __shared__ float ws[4];
  const int lane = threadIdx.x & 63;
  const int wid = threadIdx.x >> 6;
  if (lane == 0) ws[wid] = val;
  __syncthreads();
  if (threadIdx.x == 0) {
    partials[blockIdx.x] = ws[0] + ws[1] + ws[2] + ws[3];  // NO atomic
  }
}

__global__ __launch_bounds__(256) void reduce_kernel(
    const float* __restrict__ partials, float* __restrict__ out) {
  float s = 0.0f;
  for (int i = threadIdx.x; i < kBlocks; i += 256) s += partials[i];
#pragma unroll
  for (int off = 32; off > 0; off >>= 1) s += __shfl_down(s, off, 64);
  __shared__ float ws[4];
  const int lane = threadIdx.x & 63;
  const int wid = threadIdx.x >> 6;
  if (lane == 0) ws[wid] = s;
  __syncthreads();
  if (threadIdx.x == 0) {
    out[0] = (ws[0] + ws[1] + ws[2] + ws[3]) * (1.0f / kBS);  // exact 2^-14
  }
}

}  // namespace

extern "C" void kernel_launch(void* const* d_in, const int* in_sizes, int n_in,
                              void* d_out, int out_size, void* d_ws, size_t ws_size,
                              hipStream_t stream) {
  const float* outputs = (const float*)d_in[0];
  const float* gt_boxes = (const float*)d_in[1];
  const int* gt_labels = (const int*)d_in[2];
  float* out = (float*)d_out;
  float* partials = (float*)d_ws;   // kBlocks floats = 12.25 KB

  yolo_loss_kernel<<<kBlocks, 256, 0, stream>>>(outputs, gt_boxes, gt_labels, partials);
  reduce_kernel<<<1, 256, 0, stream>>>(partials, out);
}

// Round 4
// 29.855 us; speedup vs baseline: 2.0079x; 1.4201x over previous
//
#include <hip/hip_runtime.h>

namespace {

constexpr int kS = 7;
constexpr int kB = 2;
constexpr int kC = 20;
constexpr int kN = 8;
constexpr int kBS = 16384;
constexpr int kCells = kBS * kS * kS;          // 802816 = 3136 * 256 exactly
constexpr int kBlocks = kCells / 256;          // 3136
constexpr int kF = kB * 5 + kC;                // 30 floats per cell
constexpr float kLambdaCoord = 5.0f;
constexpr float kLambdaNoobj = 0.5f;
constexpr float kEps = 1e-6f;

__global__ __launch_bounds__(256) void yolo_loss_kernel(
    const float* __restrict__ outputs,   // [BS,7,7,30]
    const float* __restrict__ gt_boxes,  // [BS,8,4]
    const int* __restrict__ gt_labels,   // [BS,8]
    float* __restrict__ partials) {      // [kBlocks]
  __shared__ float lds[256 * kF];        // 30 KB: one block = 256 cells

  const int tid = threadIdx.x;
  const int c0 = blockIdx.x * 256;
  const int bs = (c0 + tid) / (kS * kS);

  // ---- issue per-thread gt loads FIRST so their latency hides under staging
  float g[kN][4];
  const float4* gb4 = reinterpret_cast<const float4*>(gt_boxes + (size_t)bs * kN * 4);
#pragma unroll
  for (int n = 0; n < kN; ++n) {
    float4 v = gb4[n];
    g[n][0] = v.x; g[n][1] = v.y; g[n][2] = v.z; g[n][3] = v.w;
  }
  const int4* lb4 = reinterpret_cast<const int4*>(gt_labels + (size_t)bs * kN);
  const int4 lab0 = lb4[0];
  const int4 lab1 = lb4[1];

  // ---- stage this block's 256 cells into LDS, fully coalesced float4 ----
  //      256 cells * 30 floats = 7680 floats = 1920 float4.
  {
    const float4* src = reinterpret_cast<const float4*>(outputs + (size_t)c0 * kF);
    float4* dst = reinterpret_cast<float4*>(lds);
#pragma unroll
    for (int i = tid; i < 1920; i += 256) dst[i] = src[i];
  }
  __syncthreads();

  // per-thread cell view in LDS; word-stride 30 across lanes -> 2-way bank
  // aliasing only (free on CDNA4)
  const float* x = lds + tid * kF;

  // ---- pairwise IOU iou[b][n] ----
  float iou[kB][kN];
#pragma unroll
  for (int b = 0; b < kB; ++b) {
    const float px = x[b * 5 + 0], py = x[b * 5 + 1];
    const float pw = x[b * 5 + 2], ph = x[b * 5 + 3];
    const float px1 = px - pw * 0.5f, px2 = px + pw * 0.5f;
    const float py1 = py - ph * 0.5f, py2 = py + ph * 0.5f;
    const float parea = pw * ph;
#pragma unroll
    for (int n = 0; n < kN; ++n) {
      const float gx = g[n][0], gy = g[n][1], gw = g[n][2], gh = g[n][3];
      const float gx1 = gx - gw * 0.5f, gx2 = gx + gw * 0.5f;
      const float gy1 = gy - gh * 0.5f, gy2 = gy + gh * 0.5f;
      const float iw = fmaxf(fminf(px2, gx2) - fmaxf(px1, gx1), 0.0f);
      const float ih = fmaxf(fminf(py2, gy2) - fmaxf(py1, gy1), 0.0f);
      const float inter = iw * ih;
      const float uni = parea + gw * gh - inter;
      iou[b][n] = inter / (uni + kEps);
    }
  }

  // ---- j_star scan (first-max wins, matches jnp.argmax) ----
  float best_iou = -1.0f;
  float i0j = 0.0f, i1j = 0.0f;
#pragma unroll
  for (int n = 0; n < kN; ++n) {
    const float m = fmaxf(iou[0][n], iou[1][n]);
    if (m > best_iou) {
      best_iou = m;
      i0j = iou[0][n];
      i1j = iou[1][n];
    }
  }
  const int bb = (i1j > i0j) ? 1 : 0;   // index 0 wins ties

  // ---- selections (reference quirk: best_b indexes gt_boxes' N axis) ----
  const float gsx = bb ? g[1][0] : g[0][0];
  const float gsy = bb ? g[1][1] : g[0][1];
  const float gsw = bb ? g[1][2] : g[0][2];
  const float gsh = bb ? g[1][3] : g[0][3];
  const float psx = bb ? x[5] : x[0];
  const float psy = bb ? x[6] : x[1];
  const float psw = bb ? x[7] : x[2];
  const float psh = bb ? x[8] : x[3];
  const float psc = bb ? x[9] : x[4];

  // ---- localization + confidence ----
  const float dx = psx - gsx;
  const float dy = psy - gsy;
  const float dw = sqrtf(psw) - sqrtf(gsw);
  const float dh = sqrtf(psh) - sqrtf(gsh);
  const float loc = kLambdaCoord * (dx * dx + dy * dy + dw * dw + dh * dh);
  const float conf_obj = (psc - best_iou) * (psc - best_iou);

  // ---- log-softmax over the 20 classes ----
  float mx = x[10];
#pragma unroll
  for (int k = 1; k < kC; ++k) mx = fmaxf(mx, x[10 + k]);
  float se = 0.0f;
#pragma unroll
  for (int k = 0; k < kC; ++k) se += __expf(x[10 + k] - mx);
  const float lse = mx + __logf(se);

  // ---- CE: mean over the 8 labels; dynamic LDS index (no scratch) ----
  float ce = 0.0f;
  ce += x[10 + lab0.x] + x[10 + lab0.y] + x[10 + lab0.z] + x[10 + lab0.w];
  ce += x[10 + lab1.x] + x[10 + lab1.y] + x[10 + lab1.z] + x[10 + lab1.w];
  ce = -(ce - 8.0f * lse) * (1.0f / kN);

  // ---- noobj ----
  const float noobj = kLambdaNoobj * (x[4] * x[4] + x[9] * x[9]);

  float val = (best_iou > 0.0f) ? (loc + conf_obj + ce) : noobj;

  // ---- block reduction: wave64 shuffle, then LDS across the 4 waves ----
#pragma unroll
  for (int off = 32; off > 0; off >>= 1) val += __shfl_down(val, off, 64);
  __shared__ float ws[4];
  const int lane = tid & 63;
  const int wid = tid >> 6;
  if (lane == 0) ws[wid] = val;
  __syncthreads();
  if (tid == 0) {
    partials[blockIdx.x] = ws[0] + ws[1] + ws[2] + ws[3];  // NO atomic
  }
}

__global__ __launch_bounds__(256) void reduce_kernel(
    const float* __restrict__ partials, float* __restrict__ out) {
  float s = 0.0f;
  for (int i = threadIdx.x; i < kBlocks; i += 256) s += partials[i];
#pragma unroll
  for (int off = 32; off > 0; off >>= 1) s += __shfl_down(s, off, 64);
  __shared__ float ws[4];
  const int lane = threadIdx.x & 63;
  const int wid = threadIdx.x >> 6;
  if (lane == 0) ws[wid] = s;
  __syncthreads();
  if (threadIdx.x == 0) {
    out[0] = (ws[0] + ws[1] + ws[2] + ws[3]) * (1.0f / kBS);  // exact 2^-14
  }
}

}  // namespace

extern "C" void kernel_launch(void* const* d_in, const int* in_sizes, int n_in,
                              void* d_out, int out_size, void* d_ws, size_t ws_size,
                              hipStream_t stream) {
  const float* outputs = (const float*)d_in[0];
  const float* gt_boxes = (const float*)d_in[1];
  const int* gt_labels = (const int*)d_in[2];
  float* out = (float*)d_out;
  float* partials = (float*)d_ws;   // kBlocks floats = 12.25 KB

  yolo_loss_kernel<<<kBlocks, 256, 0, stream>>>(outputs, gt_boxes, gt_labels, partials);
  reduce_kernel<<<1, 256, 0, stream>>>(partials, out);
}